// Round 1
// baseline (6078.222 us; speedup 1.0000x reference)
//
#include <hip/hip_runtime.h>
#include <cstdint>
#include <cstddef>

typedef unsigned short u16;
typedef __attribute__((ext_vector_type(4))) float f32x4;
typedef __attribute__((ext_vector_type(8))) short s16x8;

#define T_STEPS 512
#define OUT_MAIN 16777216   // 512*64*512
#define HSLOT 65536         // 8 groups * 16 rows * 512 (elements per parity slot)

// ---------- bf16 split helpers (bit-level, RNE; inputs are finite) ----------
__device__ __forceinline__ u16 f2bf(float f) {
  unsigned u = __builtin_bit_cast(unsigned, f);
  unsigned r = u + 0x7FFFu + ((u >> 16) & 1u);
  return (u16)(r >> 16);
}
__device__ __forceinline__ float bf2f(u16 h) {
  unsigned u = ((unsigned)h) << 16;
  return __builtin_bit_cast(float, u);
}

// ---------- init: W_x transpose+split, h0/c0 staging, zero pads/counters ----------
__global__ void init_k(const float* __restrict__ W, const float* __restrict__ h0,
                       const float* __restrict__ c0,
                       u16* __restrict__ wthi, u16* __restrict__ wtlo,
                       u16* __restrict__ hbhi, u16* __restrict__ hblo,
                       float* __restrict__ cws, unsigned long long* __restrict__ cnt) {
  const int NW = 512 * 2048;   // 1048576 (Wx part only)
  const int NH = 64 * 512;     // 32768
  const int total = NW + 3 * NH + 256;
  for (int idx = blockIdx.x * blockDim.x + threadIdx.x; idx < total;
       idx += gridDim.x * blockDim.x) {
    if (idx < NW) {
      int k = idx >> 11;          // row of W (input dim)
      int c = idx & 2047;         // gate column
      float wv = W[idx];
      u16 hi = f2bf(wv);
      wthi[c * 512 + k] = hi;
      wtlo[c * 512 + k] = f2bf(wv - bf2f(hi));
    } else if (idx < NW + NH) {
      int r = idx - NW; int b = r >> 9; int k = r & 511;
      int g = b >> 3, rr = b & 7;
      float v = h0[r];
      u16 hi = f2bf(v);
      int pos = (g * 16 + rr) * 512 + k;   // slot 0 only (t=0 reads slot 0)
      hbhi[pos] = hi;
      hblo[pos] = f2bf(v - bf2f(hi));
    } else if (idx < NW + 2 * NH) {
      int r = idx - NW - NH;
      cws[r] = c0[r];
    } else if (idx < NW + 3 * NH) {
      // zero pad rows 8..15 of both parity slots (MFMA M=16 padding)
      int r = idx - NW - 2 * NH;           // 8 groups * 8 rows * 512
      int g = r >> 12;
      int rem = r & 4095;
      int row = 8 + (rem >> 9);
      int k = rem & 511;
      int pos = (g * 16 + row) * 512 + k;
      hbhi[pos] = 0; hblo[pos] = 0;
      hbhi[HSLOT + pos] = 0; hblo[HSLOT + pos] = 0;
    } else {
      cnt[idx - NW - 3 * NH] = 0ull;
    }
  }
}

// ---------- x chunk -> bf16 hi/lo ----------
__global__ void convx_k(const float* __restrict__ x, u16* __restrict__ hi,
                        u16* __restrict__ lo, int n4) {
  for (int i = blockIdx.x * blockDim.x + threadIdx.x; i < n4;
       i += gridDim.x * blockDim.x) {
    float4 v = ((const float4*)x)[i];
    ushort4 h, l2;
    h.x = f2bf(v.x); l2.x = f2bf(v.x - bf2f(h.x));
    h.y = f2bf(v.y); l2.y = f2bf(v.y - bf2f(h.y));
    h.z = f2bf(v.z); l2.z = f2bf(v.z - bf2f(h.z));
    h.w = f2bf(v.w); l2.w = f2bf(v.w - bf2f(h.w));
    ((ushort4*)hi)[i] = h;
    ((ushort4*)lo)[i] = l2;
  }
}

// ---------- G = x@Wx + b : 128x128 tile, 4 waves, 3-term bf16-split MFMA ----------
__global__ void __launch_bounds__(256, 2)
gemm_k(const u16* __restrict__ xhi, const u16* __restrict__ xlo,
       const u16* __restrict__ wthi, const u16* __restrict__ wtlo,
       const float* __restrict__ bias, float* __restrict__ Gout) {
  __shared__ u16 Ah[4096], Al[4096], Bh[4096], Bl[4096];   // [128][32] each
  const int tid = threadIdx.x;
  const int nb = blockIdx.x & 15;
  const int mb = blockIdx.x >> 4;
  const int w = tid >> 6, l = tid & 63;
  const int wm = w >> 1, wn = w & 1;
  const int lr = l & 15, lq = l >> 4;

  const int pos0 = tid, pos1 = tid + 256;
  const int row0 = pos0 >> 2, row1 = pos1 >> 2;
  const int cc = (tid & 3) * 8;
  const size_t aOff0 = (size_t)(mb * 128 + row0) * 512 + cc;
  const size_t aOff1 = (size_t)(mb * 128 + row1) * 512 + cc;
  const size_t bOff0 = (size_t)(nb * 128 + row0) * 512 + cc;
  const size_t bOff1 = (size_t)(nb * 128 + row1) * 512 + cc;

  float bv[4];
  #pragma unroll
  for (int n = 0; n < 4; ++n) bv[n] = bias[nb * 128 + wn * 64 + n * 16 + lr];

  f32x4 acc[4][4] = {};
  s16x8 rA0, rA1, rAl0, rAl1, rB0, rB1, rBl0, rBl1;
  rA0  = *(const s16x8*)(xhi  + aOff0);
  rA1  = *(const s16x8*)(xhi  + aOff1);
  rAl0 = *(const s16x8*)(xlo  + aOff0);
  rAl1 = *(const s16x8*)(xlo  + aOff1);
  rB0  = *(const s16x8*)(wthi + bOff0);
  rB1  = *(const s16x8*)(wthi + bOff1);
  rBl0 = *(const s16x8*)(wtlo + bOff0);
  rBl1 = *(const s16x8*)(wtlo + bOff1);

  for (int kt = 0; kt < 16; ++kt) {
    *(s16x8*)&Ah[pos0 * 8] = rA0;  *(s16x8*)&Ah[pos1 * 8] = rA1;
    *(s16x8*)&Al[pos0 * 8] = rAl0; *(s16x8*)&Al[pos1 * 8] = rAl1;
    *(s16x8*)&Bh[pos0 * 8] = rB0;  *(s16x8*)&Bh[pos1 * 8] = rB1;
    *(s16x8*)&Bl[pos0 * 8] = rBl0; *(s16x8*)&Bl[pos1 * 8] = rBl1;
    __syncthreads();
    if (kt < 15) {
      const int k0 = (kt + 1) * 32;
      rA0  = *(const s16x8*)(xhi  + aOff0 + k0);
      rA1  = *(const s16x8*)(xhi  + aOff1 + k0);
      rAl0 = *(const s16x8*)(xlo  + aOff0 + k0);
      rAl1 = *(const s16x8*)(xlo  + aOff1 + k0);
      rB0  = *(const s16x8*)(wthi + bOff0 + k0);
      rB1  = *(const s16x8*)(wthi + bOff1 + k0);
      rBl0 = *(const s16x8*)(wtlo + bOff0 + k0);
      rBl1 = *(const s16x8*)(wtlo + bOff1 + k0);
    }
    s16x8 fAh[4], fAl[4], fBh[4], fBl[4];
    #pragma unroll
    for (int mm = 0; mm < 4; ++mm) {
      const int rrow = wm * 64 + mm * 16 + lr;
      fAh[mm] = *(const s16x8*)&Ah[rrow * 32 + lq * 8];
      fAl[mm] = *(const s16x8*)&Al[rrow * 32 + lq * 8];
    }
    #pragma unroll
    for (int nn = 0; nn < 4; ++nn) {
      const int crow = wn * 64 + nn * 16 + lr;
      fBh[nn] = *(const s16x8*)&Bh[crow * 32 + lq * 8];
      fBl[nn] = *(const s16x8*)&Bl[crow * 32 + lq * 8];
    }
    #pragma unroll
    for (int mm = 0; mm < 4; ++mm)
      #pragma unroll
      for (int nn = 0; nn < 4; ++nn) {
        acc[mm][nn] = __builtin_amdgcn_mfma_f32_16x16x32_bf16(fAh[mm], fBh[nn], acc[mm][nn], 0, 0, 0);
        acc[mm][nn] = __builtin_amdgcn_mfma_f32_16x16x32_bf16(fAh[mm], fBl[nn], acc[mm][nn], 0, 0, 0);
        acc[mm][nn] = __builtin_amdgcn_mfma_f32_16x16x32_bf16(fAl[mm], fBh[nn], acc[mm][nn], 0, 0, 0);
      }
    __syncthreads();
  }
  #pragma unroll
  for (int mm = 0; mm < 4; ++mm)
    #pragma unroll
    for (int nn = 0; nn < 4; ++nn)
      #pragma unroll
      for (int i = 0; i < 4; ++i) {
        const int row = mb * 128 + wm * 64 + mm * 16 + lq * 4 + i;
        const int col = nb * 128 + wn * 64 + nn * 16 + lr;
        Gout[(size_t)row * 2048 + col] = acc[mm][nn][i] + bv[nn];
      }
}

// ---------- recurrence: 8 XCD-groups x 32 CUs; Wh in registers; group barrier ----------
__global__ void __launch_bounds__(512, 2)
rec_k(const float* __restrict__ W, const float* __restrict__ Gbuf,
      u16* __restrict__ hbhi, u16* __restrict__ hblo,
      float* __restrict__ cws, float* __restrict__ out,
      unsigned long long* __restrict__ cnt, int t0, int Tc) {
  const int g = blockIdx.x & 7;        // group (XCD heuristic: blockIdx % 8)
  const int m = blockIdx.x >> 3;       // member 0..31: owns hidden units [16m,16m+16)
  const int tid = threadIdx.x;
  const int w = tid >> 6, l = tid & 63;
  const int lr = l & 15, lq = l >> 4;

  __shared__ float part[8][8][64];     // [wave][batch row][gate col]
  __shared__ float gl[8][64];          // reduced gates [batch][4*16]
  __shared__ float cL[8][16];          // persistent cell state slice

  // ---- one-time: gather Wh slice into registers as bf16 hi/lo B-fragments ----
  // wave w covers K-slice [64w, 64w+64); ntile = gate (col block g4*512 + 16m + c)
  s16x8 bhi[2][4], blo[2][4];
  #pragma unroll
  for (int kt = 0; kt < 2; ++kt)
    #pragma unroll
    for (int nt = 0; nt < 4; ++nt) {
      s16x8 vh, vl;
      #pragma unroll
      for (int j = 0; j < 8; ++j) {
        int k = w * 64 + kt * 32 + lq * 8 + j;
        int col = nt * 512 + m * 16 + lr;
        float wv = W[(size_t)(512 + k) * 2048 + col];
        u16 hb = f2bf(wv);
        vh[j] = (short)hb;
        vl[j] = (short)f2bf(wv - bf2f(hb));
      }
      bhi[kt][nt] = vh; blo[kt][nt] = vl;
    }
  if (tid < 128) {
    int b = tid >> 4, jj = tid & 15;
    cL[b][jj] = cws[(size_t)(g * 8 + b) * 512 + m * 16 + jj];
  }
  __syncthreads();

  unsigned long long* mycnt = cnt + g * 32;
  const int b5 = tid >> 6, gc = tid & 63;
  const int g4 = gc >> 4, jj5 = gc & 15;

  for (int tl = 0; tl < Tc; ++tl) {
    const int t = t0 + tl;
    // prefetch this step's x-gate contribution (independent of h -> before barrier)
    float Gv = Gbuf[((size_t)(tl * 64 + g * 8 + b5)) * 2048 + g4 * 512 + m * 16 + jj5];

    // group barrier: wait until all 32 members finished step t-1
    if (tid == 0) {
      const unsigned long long target = 32ull * (unsigned long long)t;
      while (__hip_atomic_load(mycnt, __ATOMIC_ACQUIRE, __HIP_MEMORY_SCOPE_AGENT) < target) {
        __builtin_amdgcn_s_sleep(8);
      }
    }
    __syncthreads();

    // A-fragments: h (bf16 hi/lo) from parity slot t&1
    const int slot = (t & 1) * HSLOT;
    s16x8 ahi[2], alo[2];
    #pragma unroll
    for (int kt = 0; kt < 2; ++kt) {
      const size_t off = (size_t)slot + (size_t)(g * 16 + lr) * 512 + (w * 64 + kt * 32 + lq * 8);
      ahi[kt] = *(const s16x8*)(hbhi + off);
      alo[kt] = *(const s16x8*)(hblo + off);
    }
    f32x4 acc[4] = {};
    #pragma unroll
    for (int kt = 0; kt < 2; ++kt)
      #pragma unroll
      for (int nt = 0; nt < 4; ++nt) {
        acc[nt] = __builtin_amdgcn_mfma_f32_16x16x32_bf16(ahi[kt], bhi[kt][nt], acc[nt], 0, 0, 0);
        acc[nt] = __builtin_amdgcn_mfma_f32_16x16x32_bf16(ahi[kt], blo[kt][nt], acc[nt], 0, 0, 0);
        acc[nt] = __builtin_amdgcn_mfma_f32_16x16x32_bf16(alo[kt], bhi[kt][nt], acc[nt], 0, 0, 0);
      }
    // store per-wave partial C (only real rows 0..7 -> lanes 0..31)
    if (l < 32) {
      #pragma unroll
      for (int nt = 0; nt < 4; ++nt)
        #pragma unroll
        for (int i = 0; i < 4; ++i)
          part[w][lq * 4 + i][nt * 16 + lr] = acc[nt][i];
    }
    __syncthreads();
    // reduce 8 K-slice partials + x-gate
    float s = Gv;
    #pragma unroll
    for (int w8 = 0; w8 < 8; ++w8) s += part[w8][b5][gc];
    gl[b5][gc] = s;
    __syncthreads();
    // elementwise LSTM cell update
    if (tid < 128) {
      int b = tid >> 4, jj = tid & 15;
      float fg = gl[b][jj];
      float ig = gl[b][16 + jj];
      float cg = gl[b][32 + jj];
      float og = gl[b][48 + jj];
      float fs = 1.f / (1.f + __expf(-fg));
      float is = 1.f / (1.f + __expf(-ig));
      float os = 1.f / (1.f + __expf(-og));
      float cd = tanhf(cg);
      float cn = fs * cL[b][jj] + is * cd;
      float hn = os * tanhf(cn);
      cL[b][jj] = cn;
      const int bgl = g * 8 + b;
      const int j = m * 16 + jj;
      out[((size_t)t * 64 + bgl) * 512 + j] = hn;
      cws[(size_t)bgl * 512 + j] = cn;
      const int wslot = ((t + 1) & 1) * HSLOT;
      u16 hh = f2bf(hn);
      hbhi[wslot + (size_t)(g * 16 + b) * 512 + j] = hh;
      hblo[wslot + (size_t)(g * 16 + b) * 512 + j] = f2bf(hn - bf2f(hh));
      if (t == T_STEPS - 1) {
        out[(size_t)OUT_MAIN + (size_t)bgl * 512 + j] = hn;
        out[(size_t)OUT_MAIN + 32768 + (size_t)bgl * 512 + j] = cn;
      }
    }
    __syncthreads();   // all stores drained to L2 before release
    if (tid == 0)
      __hip_atomic_fetch_add(mycnt, 1, __ATOMIC_RELEASE, __HIP_MEMORY_SCOPE_AGENT);
  }
}

// ---------- host ----------
extern "C" void kernel_launch(void* const* d_in, const int* in_sizes, int n_in,
                              void* d_out, int out_size, void* d_ws, size_t ws_size,
                              hipStream_t stream) {
  const float* x  = (const float*)d_in[0];
  const float* h0 = (const float*)d_in[1];
  const float* c0 = (const float*)d_in[2];
  const float* W  = (const float*)d_in[3];
  const float* bs = (const float*)d_in[4];
  float* out = (float*)d_out;

  // workspace budget -> chunk length Tc (timesteps of G precompute per pass)
  auto need = [](int tc) -> size_t {
    size_t s = 0;
    s += (size_t)tc * 524288;     // G fp32
    s += (size_t)tc * 131072;     // x hi+lo bf16
    s += 2 * (size_t)2097152;     // WxT hi+lo
    s += 2 * (size_t)262144;      // hbuf hi+lo (2 slots)
    s += 131072;                  // c state
    s += 2048 + 8192;             // counters + alignment slack
    return s;
  };
  int Tc = 512;
  while (Tc > 2 && need(Tc) > ws_size) Tc >>= 1;

  char* p = (char*)d_ws;
  auto alloc = [&](size_t bytes) -> char* {
    char* r = p;
    p += (bytes + 255) & ~(size_t)255;
    return r;
  };
  float* Gbuf = (float*)alloc((size_t)Tc * 524288);
  u16* xhi  = (u16*)alloc((size_t)Tc * 65536);
  u16* xlo  = (u16*)alloc((size_t)Tc * 65536);
  u16* wthi = (u16*)alloc(2097152);
  u16* wtlo = (u16*)alloc(2097152);
  u16* hbhi = (u16*)alloc(262144);
  u16* hblo = (u16*)alloc(262144);
  float* cws = (float*)alloc(131072);
  unsigned long long* cnt = (unsigned long long*)alloc(2048);

  hipLaunchKernelGGL(init_k, dim3(1024), dim3(256), 0, stream,
                     W, h0, c0, wthi, wtlo, hbhi, hblo, cws, cnt);
  const int nch = 512 / Tc;
  for (int ck = 0; ck < nch; ++ck) {
    const float* xck = x + (size_t)ck * Tc * 64 * 512;
    int n4 = Tc * 64 * 512 / 4;
    hipLaunchKernelGGL(convx_k, dim3(1024), dim3(256), 0, stream, xck, xhi, xlo, n4);
    hipLaunchKernelGGL(gemm_k, dim3(Tc / 2 * 16), dim3(256), 0, stream,
                       xhi, xlo, wthi, wtlo, bs, Gbuf);
    hipLaunchKernelGGL(rec_k, dim3(256), dim3(512), 0, stream,
                       W, Gbuf, hbhi, hblo, cws, out, cnt, ck * Tc, Tc);
  }
}